// Round 10
// baseline (356988.379 us; speedup 1.0000x reference)
//
#include <hip/hip_runtime.h>
#include <stdint.h>

typedef unsigned long long u64;
typedef float f32x32 __attribute__((ext_vector_type(32)));
typedef float f32x16 __attribute__((ext_vector_type(16)));

#define T_TOTAL 65536
#define ISZ 256
#define HSZ 512
#define NWORK 16
#define SLICE 32   // HSZ / NWORK
#define CTHR 512   // compute threads (8 waves)
#define NTHR 576   // + 64 service threads (1 wave)

// LDS skew (word index): +4 words per row -> max 2-way bank aliasing (free).
__device__ __forceinline__ int HSW(int i) { return i + ((i >> 5) << 2); }  // rows of 32
__device__ __forceinline__ int XSW(int i) { return i + ((i >> 4) << 2); }  // rows of 16

struct Ctl { int grank; int chosen; int fastctr; int done; int slowctr; int pad[11]; };

// Poll = genuine TCC-executed atomic RMW (add 0, sc0 returns old value).
// Inline asm so InstCombine cannot demote the idempotent RMW to an atomic
// LOAD (every load-path poll read stale L1 data: R3/R4/R5/R7 evidence).
__device__ __forceinline__ u64 poll1_rmw(u64* p, unsigned sv, long long& budget) {
  u64 q, zero = 0;
  for (;;) {
    asm volatile("global_atomic_add_x2 %0, %1, %2, off sc0\n\t"
                 "s_waitcnt vmcnt(0)"
                 : "=&v"(q) : "v"(p), "v"(zero) : "memory");
    if ((unsigned)(q >> 32) == sv) break;
    if (--budget <= 0) break;
  }
  return q;
}
__device__ __forceinline__ void publish_rmw(u64* p, u64 v) {
  asm volatile("global_atomic_swap_x2 %0, %1, off" :: "v"(p), "v"(v) : "memory");
}

// ---------------------------------------------------------------------------
// Persistent fused GRU scan, 16 blocks x (512 compute + 64 service) threads.
// R8 chain bloat removed: compute waves touch vmem ONLY via their poll RMW
// and (epilogue lanes) one L2 swap; the service wave absorbs x staging (with
// a full step of vmcnt slack) and the out[] HBM stores (hq LDS handoff).
// NO LAMBDA (R9 post-mortem: by-ref lambda captures sent the weight vectors
// to scratch, FETCH 1.2 GB/dispatch); body is a macro, 2x manual unroll for
// the statically-indexed x register pipeline; weights loaded unconditionally.
//
// Sync: tagged 64-bit slots {tag=version, f32 value}, 16B-padded, parity-2
// ring. FAST mode (16 workers verified on ONE XCD): TCC atomic RMWs.
// SLOW fallback: agent-scope acquire/release (R2-proven).
//
// Barriers: B2 (h polled -> LDS ready), B3 (hq + buffer turnover).
//  - h_lds/x_lds parity double-buffered (R6/R8 safety argument).
//  - hq: service reads pre-B2(s); epilogue writes post-B2(s) pre-B3(s);
//    next service read is post-B3(s). No overlap.
// Spin fuse bounds worst-case runtime (fail visibly, never wedge).
// ---------------------------------------------------------------------------
__global__ __launch_bounds__(NTHR, 1) void gru_fused(
    const float* __restrict__ xs, const float* __restrict__ w_ih,
    const float* __restrict__ w_hh, const float* __restrict__ bias,
    const float* __restrict__ bias_n, u64* __restrict__ hslot,
    Ctl* __restrict__ ctl, float* __restrict__ out) {
  const int tid = threadIdx.x;
  const bool is_svc = tid >= CTHR;
  const int svc = tid - CTHR;       // 0..63 for the service wave
  const int seg = tid & 15;         // compute: K-segment
  const int rg  = tid >> 4;         // compute: unit within slice

  __shared__ int s_role, s_fast;
  __shared__ __align__(16) float x_lds[2][320];
  __shared__ __align__(16) float h_lds[2][576];
  __shared__ float hq[32];          // epilogue -> service handoff (h_{s+1})

  // ---- election: verify 16 blocks on one XCD, else agent-scope fallback
  if (tid == 0) {
    unsigned xcc = 0;
    asm volatile("s_getreg_b32 %0, hwreg(HW_REG_XCC_ID)" : "=s"(xcc));
    long long eb = 100000000;
    int rank = __hip_atomic_fetch_add(&ctl->grank, 1, __ATOMIC_RELAXED,
                                      __HIP_MEMORY_SCOPE_AGENT);
    if (rank == 0)
      __hip_atomic_store(&ctl->chosen, (int)xcc + 1, __ATOMIC_RELEASE,
                         __HIP_MEMORY_SCOPE_AGENT);
    int chosen;
    do { chosen = __hip_atomic_load(&ctl->chosen, __ATOMIC_ACQUIRE,
                                    __HIP_MEMORY_SCOPE_AGENT); }
    while (chosen == 0 && --eb > 0);
    int fr = -1;
    if ((int)xcc == chosen - 1)
      fr = __hip_atomic_fetch_add(&ctl->fastctr, 1, __ATOMIC_RELAXED,
                                  __HIP_MEMORY_SCOPE_AGENT);
    __hip_atomic_fetch_add(&ctl->done, 1, __ATOMIC_ACQ_REL,
                           __HIP_MEMORY_SCOPE_AGENT);
    int dn;
    do { dn = __hip_atomic_load(&ctl->done, __ATOMIC_ACQUIRE,
                                __HIP_MEMORY_SCOPE_AGENT); }
    while (dn < (int)gridDim.x && --eb > 0);
    int fc = __hip_atomic_load(&ctl->fastctr, __ATOMIC_ACQUIRE,
                               __HIP_MEMORY_SCOPE_AGENT);
    int fast = (fc >= NWORK && dn >= (int)gridDim.x) ? 1 : 0;
    int role = -1;
    if (fast) {
      if (fr >= 0 && fr < NWORK) role = fr;
    } else {
      int sr = __hip_atomic_fetch_add(&ctl->slowctr, 1, __ATOMIC_RELAXED,
                                      __HIP_MEMORY_SCOPE_AGENT);
      if (sr < NWORK) role = sr;
    }
    s_role = role; s_fast = fast;
  }
  __syncthreads();
  const int role = s_role;   // uniform per block
  const int fast = s_fast;
  if (role < 0) return;      // whole block exits together

  // ---- weights into registers: UNCONDITIONAL load (service threads load a
  // clamped-valid row they never use; avoids conditional-init/lambda traps).
  const int myunit = role * SLICE + (rg & 31);   // valid for all 36 rg values
  f32x32 wh0, wh1, wh2;
  f32x16 wi0, wi1, wi2;
  {
    const float* h0 = w_hh + (size_t)(0 * HSZ + myunit) * HSZ + seg * 32;
    const float* h1 = w_hh + (size_t)(1 * HSZ + myunit) * HSZ + seg * 32;
    const float* h2 = w_hh + (size_t)(2 * HSZ + myunit) * HSZ + seg * 32;
#pragma unroll
    for (int u = 0; u < 8; ++u) {
      float4 a = *(const float4*)(h0 + u * 4);
      float4 b = *(const float4*)(h1 + u * 4);
      float4 c = *(const float4*)(h2 + u * 4);
      wh0[u*4+0]=a.x; wh0[u*4+1]=a.y; wh0[u*4+2]=a.z; wh0[u*4+3]=a.w;
      wh1[u*4+0]=b.x; wh1[u*4+1]=b.y; wh1[u*4+2]=b.z; wh1[u*4+3]=b.w;
      wh2[u*4+0]=c.x; wh2[u*4+1]=c.y; wh2[u*4+2]=c.z; wh2[u*4+3]=c.w;
    }
    const float* i0 = w_ih + (size_t)(0 * HSZ + myunit) * ISZ + seg * 16;
    const float* i1 = w_ih + (size_t)(1 * HSZ + myunit) * ISZ + seg * 16;
    const float* i2 = w_ih + (size_t)(2 * HSZ + myunit) * ISZ + seg * 16;
#pragma unroll
    for (int u = 0; u < 4; ++u) {
      float4 a = *(const float4*)(i0 + u * 4);
      float4 b = *(const float4*)(i1 + u * 4);
      float4 c = *(const float4*)(i2 + u * 4);
      wi0[u*4+0]=a.x; wi0[u*4+1]=a.y; wi0[u*4+2]=a.z; wi0[u*4+3]=a.w;
      wi1[u*4+0]=b.x; wi1[u*4+1]=b.y; wi1[u*4+2]=b.z; wi1[u*4+3]=b.w;
      wi2[u*4+0]=c.x; wi2[u*4+1]=c.y; wi2[u*4+2]=c.z; wi2[u*4+3]=c.w;
    }
  }
  const float br  = bias[myunit];
  const float bz  = bias[HSZ + myunit];
  const float bnn = bias[2 * HSZ + myunit];
  const float bn2 = bias_n[myunit];

  // ---- service x pipeline prologue: x[0] -> LDS buf0; xregA = x[1]
  float4 xregA{}, xregB{};
  if (is_svc) {
    float4 t0 = *(const float4*)(xs + svc * 4);
    *(float4*)&x_lds[0][XSW(svc * 4)] = t0;
    xregA = *(const float4*)(xs + (size_t)ISZ + svc * 4);
  }
  __syncthreads();

  long long budget = 20000000;  // spin fuse (fail visibly, never wedge)

#define STEP_BODY(S, XW, XL)                                                   \
  {                                                                            \
    const int cur = (S) & 1, nxt = cur ^ 1;                                    \
    float a0 = 0.f, a1 = 0.f, a2 = 0.f, a3 = 0.f;                              \
    if (is_svc) {                                                              \
      /* x[S+1] -> LDS: vmcnt wait covers only last iter's load (full-step */  \
      /* slack). Then issue x[S+2]; then out row S-1 (store stays behind   */  \
      /* the load in the queue, so next iter waits only the load).         */  \
      *(float4*)&x_lds[nxt][XSW(svc * 4)] = XW;                                \
      int srow = ((S) + 2 < T_TOTAL) ? ((S) + 2) : (T_TOTAL - 1);              \
      XL = *(const float4*)(xs + (size_t)srow * ISZ + svc * 4);                \
      if ((S) > 0 && svc < 32) {                                               \
        float hv = hq[svc];                                                    \
        out[(size_t)HSZ + (size_t)((S) - 1) * HSZ + role * SLICE + svc] = hv;  \
      }                                                                        \
    } else {                                                                   \
      _Pragma("unroll")                                                        \
      for (int u = 0; u < 4; ++u) {                                            \
        float4 xv = *(const float4*)&x_lds[cur][XSW(seg * 16 + u * 4)];        \
        a0 += wi0[u*4+0]*xv.x + wi0[u*4+1]*xv.y + wi0[u*4+2]*xv.z + wi0[u*4+3]*xv.w; \
        a1 += wi1[u*4+0]*xv.x + wi1[u*4+1]*xv.y + wi1[u*4+2]*xv.z + wi1[u*4+3]*xv.w; \
        a2 += wi2[u*4+0]*xv.x + wi2[u*4+1]*xv.y + wi2[u*4+2]*xv.z + wi2[u*4+3]*xv.w; \
      }                                                                        \
      u64* sb = hslot + (size_t)cur * (HSZ * 2);                               \
      u64 q0;                                                                  \
      if (fast) {                                                              \
        q0 = poll1_rmw(&sb[2 * tid], (unsigned)(S), budget);                   \
      } else {                                                                 \
        do {                                                                   \
          q0 = __hip_atomic_load(&sb[2 * tid], __ATOMIC_ACQUIRE,               \
                                 __HIP_MEMORY_SCOPE_AGENT);                    \
        } while ((unsigned)(q0 >> 32) != (unsigned)(S) && --budget > 0);       \
      }                                                                        \
      h_lds[cur][HSW(tid)] = __uint_as_float((unsigned)q0);                    \
    }                                                                          \
    __syncthreads(); /* B2: h ready */                                         \
    if (!is_svc) {                                                             \
      _Pragma("unroll")                                                        \
      for (int u = 0; u < 8; ++u) {                                            \
        float4 hv = *(const float4*)&h_lds[cur][HSW(seg * 32 + u * 4)];        \
        a0 += wh0[u*4+0]*hv.x + wh0[u*4+1]*hv.y + wh0[u*4+2]*hv.z + wh0[u*4+3]*hv.w; \
        a1 += wh1[u*4+0]*hv.x + wh1[u*4+1]*hv.y + wh1[u*4+2]*hv.z + wh1[u*4+3]*hv.w; \
        a3 += wh2[u*4+0]*hv.x + wh2[u*4+1]*hv.y + wh2[u*4+2]*hv.z + wh2[u*4+3]*hv.w; \
      }                                                                        \
      _Pragma("unroll")                                                        \
      for (int p = 0; p < 4; ++p) {                                            \
        int m = 1 << p;                                                        \
        a0 += __shfl_xor(a0, m, 64);                                           \
        a1 += __shfl_xor(a1, m, 64);                                           \
        a2 += __shfl_xor(a2, m, 64);                                           \
        a3 += __shfl_xor(a3, m, 64);                                           \
      }                                                                        \
      if (seg == 0) { /* one lane per unit: epilogue, publish, hq handoff */   \
        float r  = 1.f / (1.f + __expf(-(br + a0)));                           \
        float z  = 1.f / (1.f + __expf(-(bz + a1)));                           \
        float tv = bnn + a2 + r * (a3 + bn2);                                  \
        float nn = 1.f - 2.f / (__expf(2.f * tv) + 1.f);                       \
        float hold = h_lds[cur][HSW(myunit)];                                  \
        float hnew = nn + z * (hold - nn);                                     \
        u64 pw = ((u64)(unsigned)((S) + 1) << 32) | (u64)__float_as_uint(hnew);\
        u64* pp = &hslot[(size_t)nxt * (HSZ * 2) + 2 * myunit];                \
        if (fast) publish_rmw(pp, pw);                                         \
        else __hip_atomic_store(pp, pw, __ATOMIC_RELEASE,                      \
                                __HIP_MEMORY_SCOPE_AGENT);                     \
        hq[rg] = hnew;                                                         \
      }                                                                        \
    }                                                                          \
    __syncthreads(); /* B3: hq ready; buffer turnover fence */                 \
  }

  for (int s = 0; s < T_TOTAL; s += 2) {  // 2x unroll: static x-reg pipeline
    STEP_BODY(s,     xregA, xregB)
    STEP_BODY(s + 1, xregB, xregA)
  }
#undef STEP_BODY

  // Tail: hq holds h_T (written at iter T-1, fenced by final B3).
  if (is_svc && svc < 32) {
    float hv = hq[svc];
    out[(size_t)HSZ + (size_t)(T_TOTAL - 1) * HSZ + role * SLICE + svc] = hv;
    out[role * SLICE + svc] = hv;
  }
}

// ---------------------------------------------------------------------------
extern "C" void kernel_launch(void* const* d_in, const int* in_sizes, int n_in,
                              void* d_out, int out_size, void* d_ws, size_t ws_size,
                              hipStream_t stream) {
  const float* xs     = (const float*)d_in[0];
  const float* w_ih   = (const float*)d_in[1];
  const float* w_hh   = (const float*)d_in[2];
  const float* bias   = (const float*)d_in[3];
  const float* bias_n = (const float*)d_in[4];
  float* out   = (float*)d_out;
  u64*   hslot = (u64*)d_ws;                    // [2][1024] padded slots = 16 KB
  Ctl*   ctl   = (Ctl*)((char*)d_ws + 16384);   // election control

  hipMemsetAsync(d_ws, 0, 16384 + 256, stream); // tags=0 => h_0 = 0; ctl = 0
  gru_fused<<<256, NTHR, 0, stream>>>(xs, w_ih, w_hh, bias, bias_n, hslot, ctl, out);
}

// Round 11
// 137575.464 us; speedup vs baseline: 2.5949x; 2.5949x over previous
//
#include <hip/hip_runtime.h>
#include <stdint.h>

typedef unsigned long long u64;
typedef float f32x32 __attribute__((ext_vector_type(32)));
typedef float f32x16 __attribute__((ext_vector_type(16)));

#define T_TOTAL 65536
#define ISZ 256
#define HSZ 512
#define NWORK 16
#define SLICE 32   // HSZ / NWORK
#define NTHR 512   // 8 waves: even 2/SIMD split -> 256 regs/wave budget (R10 lesson)

// LDS skew (word index): +4 words per row -> max 2-way bank aliasing (free).
__device__ __forceinline__ int HSW(int i) { return i + ((i >> 5) << 2); }  // rows of 32
__device__ __forceinline__ int XSW(int i) { return i + ((i >> 4) << 2); }  // rows of 16

struct Ctl { int grank; int chosen; int fastctr; int done; int slowctr; int pad[11]; };

// Poll = genuine TCC-executed atomic RMW (add 0, sc0 returns old value).
// Inline asm so InstCombine cannot demote the idempotent RMW to an atomic
// LOAD (every load-path poll read stale L1 data: R3/R4/R5/R7 evidence).
__device__ __forceinline__ u64 poll1_rmw(u64* p, unsigned sv, long long& budget) {
  u64 q, zero = 0;
  for (;;) {
    asm volatile("global_atomic_add_x2 %0, %1, %2, off sc0\n\t"
                 "s_waitcnt vmcnt(0)"
                 : "=&v"(q) : "v"(p), "v"(zero) : "memory");
    if ((unsigned)(q >> 32) == sv) break;
    if (--budget <= 0) break;
  }
  return q;
}
__device__ __forceinline__ void publish_rmw(u64* p, u64 v) {
  asm volatile("global_atomic_swap_x2 %0, %1, off" :: "v"(p), "v"(v) : "memory");
}

// ---------------------------------------------------------------------------
// Persistent fused GRU scan, 16 blocks x 512 threads (R8 shell: 8 waves,
// weights resident in the unified VGPR/AGPR file).
//
// R8 -> R11 change: ISSUE ORDER ONLY. All fire-and-forget vmem (x[s+1] LDS
// commit, x[s+2] load issue, out[s-1] HBM store from the hprev register) is
// issued in the shadow window right AFTER the poll succeeds, giving each op a
// full step (~1000cy) to retire before any vmcnt(0) sees it. R8 issued them
// ~100cy before the next poll, which serially drained an HBM store + loads
// every step (the 2.0us/step chain). The publish swap stays in the epilogue
// (earliest possible on the chain). R9/R10's service wave achieved the same
// but its 9th wave cut the per-wave register budget 256->~170 -> spill.
//
// Sync: tagged 64-bit slots {tag=version, f32 value}, 16B-padded, parity-2
// ring. FAST mode (16 workers verified on ONE XCD): TCC atomic RMWs.
// SLOW fallback: agent-scope acquire/release (R2-proven).
//
// ONE barrier (B2) per step. Safety: all LDS buffer writes happen post-poll,
// hence post-B2 of the previous step; parity double-buffering separates
// writer/reader buffers within a step; overwrite of buffer P at step s+2 is
// ordered after B2(s+1), and any wave passing B2(s+1) implies (block-local
// barrier) every wave finished iter s entirely. Inter-block slot overwrite
// gated by the tag protocol as in R6/R8. Spin fuse: fail visibly, never wedge.
// ---------------------------------------------------------------------------
__global__ __launch_bounds__(NTHR, 1) void gru_fused(
    const float* __restrict__ xs, const float* __restrict__ w_ih,
    const float* __restrict__ w_hh, const float* __restrict__ bias,
    const float* __restrict__ bias_n, u64* __restrict__ hslot,
    Ctl* __restrict__ ctl, float* __restrict__ out) {
  const int tid = threadIdx.x;
  const int seg = tid & 15;   // K-segment: h[32*seg..+32), x[16*seg..+16)
  const int rg  = tid >> 4;   // unit within slice (0..31)

  __shared__ int s_role, s_fast;
  __shared__ __align__(16) float x_lds[2][320];
  __shared__ __align__(16) float h_lds[2][576];

  // ---- election: verify 16 blocks on one XCD, else agent-scope fallback
  if (tid == 0) {
    unsigned xcc = 0;
    asm volatile("s_getreg_b32 %0, hwreg(HW_REG_XCC_ID)" : "=s"(xcc));
    long long eb = 100000000;
    int rank = __hip_atomic_fetch_add(&ctl->grank, 1, __ATOMIC_RELAXED,
                                      __HIP_MEMORY_SCOPE_AGENT);
    if (rank == 0)
      __hip_atomic_store(&ctl->chosen, (int)xcc + 1, __ATOMIC_RELEASE,
                         __HIP_MEMORY_SCOPE_AGENT);
    int chosen;
    do { chosen = __hip_atomic_load(&ctl->chosen, __ATOMIC_ACQUIRE,
                                    __HIP_MEMORY_SCOPE_AGENT); }
    while (chosen == 0 && --eb > 0);
    int fr = -1;
    if ((int)xcc == chosen - 1)
      fr = __hip_atomic_fetch_add(&ctl->fastctr, 1, __ATOMIC_RELAXED,
                                  __HIP_MEMORY_SCOPE_AGENT);
    __hip_atomic_fetch_add(&ctl->done, 1, __ATOMIC_ACQ_REL,
                           __HIP_MEMORY_SCOPE_AGENT);
    int dn;
    do { dn = __hip_atomic_load(&ctl->done, __ATOMIC_ACQUIRE,
                                __HIP_MEMORY_SCOPE_AGENT); }
    while (dn < (int)gridDim.x && --eb > 0);
    int fc = __hip_atomic_load(&ctl->fastctr, __ATOMIC_ACQUIRE,
                               __HIP_MEMORY_SCOPE_AGENT);
    int fast = (fc >= NWORK && dn >= (int)gridDim.x) ? 1 : 0;
    int role = -1;
    if (fast) {
      if (fr >= 0 && fr < NWORK) role = fr;
    } else {
      int sr = __hip_atomic_fetch_add(&ctl->slowctr, 1, __ATOMIC_RELAXED,
                                      __HIP_MEMORY_SCOPE_AGENT);
      if (sr < NWORK) role = sr;
    }
    s_role = role; s_fast = fast;
  }
  __syncthreads();
  const int role = s_role;   // uniform per block
  const int fast = s_fast;
  if (role < 0) return;      // whole block exits together

  // ---- weights into registers (ext_vector, static indexing; R8-proven) ----
  const int myunit = role * SLICE + rg;
  f32x32 wh0, wh1, wh2;
  f32x16 wi0, wi1, wi2;
  {
    const float* h0 = w_hh + (size_t)(0 * HSZ + myunit) * HSZ + seg * 32;
    const float* h1 = w_hh + (size_t)(1 * HSZ + myunit) * HSZ + seg * 32;
    const float* h2 = w_hh + (size_t)(2 * HSZ + myunit) * HSZ + seg * 32;
#pragma unroll
    for (int u = 0; u < 8; ++u) {
      float4 a = *(const float4*)(h0 + u * 4);
      float4 b = *(const float4*)(h1 + u * 4);
      float4 c = *(const float4*)(h2 + u * 4);
      wh0[u*4+0]=a.x; wh0[u*4+1]=a.y; wh0[u*4+2]=a.z; wh0[u*4+3]=a.w;
      wh1[u*4+0]=b.x; wh1[u*4+1]=b.y; wh1[u*4+2]=b.z; wh1[u*4+3]=b.w;
      wh2[u*4+0]=c.x; wh2[u*4+1]=c.y; wh2[u*4+2]=c.z; wh2[u*4+3]=c.w;
    }
    const float* i0 = w_ih + (size_t)(0 * HSZ + myunit) * ISZ + seg * 16;
    const float* i1 = w_ih + (size_t)(1 * HSZ + myunit) * ISZ + seg * 16;
    const float* i2 = w_ih + (size_t)(2 * HSZ + myunit) * ISZ + seg * 16;
#pragma unroll
    for (int u = 0; u < 4; ++u) {
      float4 a = *(const float4*)(i0 + u * 4);
      float4 b = *(const float4*)(i1 + u * 4);
      float4 c = *(const float4*)(i2 + u * 4);
      wi0[u*4+0]=a.x; wi0[u*4+1]=a.y; wi0[u*4+2]=a.z; wi0[u*4+3]=a.w;
      wi1[u*4+0]=b.x; wi1[u*4+1]=b.y; wi1[u*4+2]=b.z; wi1[u*4+3]=b.w;
      wi2[u*4+0]=c.x; wi2[u*4+1]=c.y; wi2[u*4+2]=c.z; wi2[u*4+3]=c.w;
    }
  }
  const float br  = bias[myunit];
  const float bz  = bias[HSZ + myunit];
  const float bnn = bias[2 * HSZ + myunit];
  const float bn2 = bias_n[myunit];

  // prologue: x[0] -> LDS buf0; xreg holds x[1]
  float4 xreg{};
  if (tid < 64) {
    float4 t0 = *(const float4*)(xs + tid * 4);
    *(float4*)&x_lds[0][XSW(tid * 4)] = t0;
    xreg = *(const float4*)(xs + (size_t)ISZ + tid * 4);
  }
  __syncthreads();

  float hprev = 0.f;            // seg==0 lanes: h value of the previous step
  long long budget = 20000000;  // spin fuse (fail visibly, never wedge)

  for (int s = 0; s < T_TOTAL; ++s) {
    const int cur = s & 1, nxt = cur ^ 1;

    // 1) Input-side gate dots (x_lds[cur], LDS only). a3 = hidden-side n.
    float a0 = 0.f, a1 = 0.f, a2 = 0.f, a3 = 0.f;
#pragma unroll
    for (int u = 0; u < 4; ++u) {
      float4 xv = *(const float4*)&x_lds[cur][XSW(seg * 16 + u * 4)];
      a0 += wi0[u*4+0]*xv.x + wi0[u*4+1]*xv.y + wi0[u*4+2]*xv.z + wi0[u*4+3]*xv.w;
      a1 += wi1[u*4+0]*xv.x + wi1[u*4+1]*xv.y + wi1[u*4+2]*xv.z + wi1[u*4+3]*xv.w;
      a2 += wi2[u*4+0]*xv.x + wi2[u*4+1]*xv.y + wi2[u*4+2]*xv.z + wi2[u*4+3]*xv.w;
    }

    // 2) Poll h version s (only vmem this wave has outstanding besides ops
    //    issued a full step ago -> near-clean vmcnt(0)).
    u64* sb = hslot + (size_t)cur * (HSZ * 2);
    u64 q0;
    if (fast) {
      q0 = poll1_rmw(&sb[2 * tid], (unsigned)s, budget);
    } else {
      do {
        q0 = __hip_atomic_load(&sb[2 * tid], __ATOMIC_ACQUIRE,
                               __HIP_MEMORY_SCOPE_AGENT);
      } while ((unsigned)(q0 >> 32) != (unsigned)s && --budget > 0);
    }
    h_lds[cur][HSW(tid)] = __uint_as_float((unsigned)q0);

    // 3) Shadow window: fire-and-forget vmem with a full step to retire.
    if (tid < 64) {
      *(float4*)&x_lds[nxt][XSW(tid * 4)] = xreg;   // commit x[s+1]
      int srow = (s + 2 < T_TOTAL) ? (s + 2) : (T_TOTAL - 1);
      xreg = *(const float4*)(xs + (size_t)srow * ISZ + tid * 4);  // issue x[s+2]
    }
    if (seg == 0 && s > 0)
      out[(size_t)HSZ + (size_t)(s - 1) * HSZ + myunit] = hprev;  // out row s-1

    __syncthreads();  // B2: h + x[nxt] staged; the only barrier per step

    // 4) Hidden-side dots (critical chain): 3 rows x 32-wide segment.
#pragma unroll
    for (int u = 0; u < 8; ++u) {
      float4 hv = *(const float4*)&h_lds[cur][HSW(seg * 32 + u * 4)];
      a0 += wh0[u*4+0]*hv.x + wh0[u*4+1]*hv.y + wh0[u*4+2]*hv.z + wh0[u*4+3]*hv.w;
      a1 += wh1[u*4+0]*hv.x + wh1[u*4+1]*hv.y + wh1[u*4+2]*hv.z + wh1[u*4+3]*hv.w;
      a3 += wh2[u*4+0]*hv.x + wh2[u*4+1]*hv.y + wh2[u*4+2]*hv.z + wh2[u*4+3]*hv.w;
    }
#pragma unroll
    for (int p = 0; p < 4; ++p) {
      int m = 1 << p;
      a0 += __shfl_xor(a0, m, 64);
      a1 += __shfl_xor(a1, m, 64);
      a2 += __shfl_xor(a2, m, 64);
      a3 += __shfl_xor(a3, m, 64);
    }

    // 5) Epilogue + publish (chain edge, issued earliest). out[] deferred to
    //    the next step's shadow window via hprev.
    if (seg == 0) {
      float r  = 1.f / (1.f + __expf(-(br + a0)));
      float z  = 1.f / (1.f + __expf(-(bz + a1)));
      float tv = bnn + a2 + r * (a3 + bn2);
      float nn = 1.f - 2.f / (__expf(2.f * tv) + 1.f);  // tanh, exact limits
      float hold = h_lds[cur][HSW(myunit)];
      float hnew = nn + z * (hold - nn);
      u64 pw = ((u64)(unsigned)(s + 1) << 32) | (u64)__float_as_uint(hnew);
      u64* pp = &hslot[(size_t)nxt * (HSZ * 2) + 2 * myunit];
      if (fast) publish_rmw(pp, pw);
      else __hip_atomic_store(pp, pw, __ATOMIC_RELEASE, __HIP_MEMORY_SCOPE_AGENT);
      hprev = hnew;
    }
  }

  // Tail: row T-1 and the final state (hprev holds h_T on seg==0 lanes).
  if (seg == 0) {
    out[(size_t)HSZ + (size_t)(T_TOTAL - 1) * HSZ + myunit] = hprev;
    out[myunit] = hprev;
  }
}

// ---------------------------------------------------------------------------
extern "C" void kernel_launch(void* const* d_in, const int* in_sizes, int n_in,
                              void* d_out, int out_size, void* d_ws, size_t ws_size,
                              hipStream_t stream) {
  const float* xs     = (const float*)d_in[0];
  const float* w_ih   = (const float*)d_in[1];
  const float* w_hh   = (const float*)d_in[2];
  const float* bias   = (const float*)d_in[3];
  const float* bias_n = (const float*)d_in[4];
  float* out   = (float*)d_out;
  u64*   hslot = (u64*)d_ws;                    // [2][1024] padded slots = 16 KB
  Ctl*   ctl   = (Ctl*)((char*)d_ws + 16384);   // election control

  hipMemsetAsync(d_ws, 0, 16384 + 256, stream); // tags=0 => h_0 = 0; ctl = 0
  gru_fused<<<256, NTHR, 0, stream>>>(xs, w_ih, w_hh, bias, bias_n, hslot, ctl, out);
}